// Round 5
// baseline (1225.221 us; speedup 1.0000x reference)
//
#include <hip/hip_runtime.h>

#define HD 1024
#define ID 1024
#define BATCH 64
#define SEQ 512
#define BS (BATCH*SEQ)     // 32768 rows
#define CHUNK 64
#define NCHUNK (SEQ/CHUNK) // 8
#define LR_OVER_I (0.01f/1024.0f)

typedef unsigned int u32;
typedef unsigned short ushort_t;
typedef __attribute__((ext_vector_type(8))) short short8;        // 8 bf16 (4 VGPRs)
typedef __attribute__((ext_vector_type(8))) unsigned short ushort8;
typedef __attribute__((ext_vector_type(4))) unsigned short ushort4v;
typedef __attribute__((ext_vector_type(4))) float floatx4;

__device__ inline ushort_t f2bf(float f) {
    union { float f; u32 u; } v; v.f = f;
    return (ushort_t)((v.u + 0x7FFFu + ((v.u >> 16) & 1u)) >> 16);  // RNE
}
__device__ inline float bf2f(ushort_t h) {
    union { u32 u; float f; } v; v.u = ((u32)h) << 16; return v.f;
}

__device__ inline void load_lds16(const void* g, void* l) {
    __builtin_amdgcn_global_load_lds(
        (const __attribute__((address_space(1))) u32*)g,
        (__attribute__((address_space(3))) u32*)l, 16, 0, 0);
}

// ---------- merged prep: convert x->bf16 | WdT/WtT/bd | 3 weight transposes ----------
// grid: [0,16384) convert; [16384,17408) prep_w tiles; [17408,20480) transposes.
__global__ void prep_all(const float* __restrict__ x, ushort_t* __restrict__ xb,
                         const float* __restrict__ Wi, const float* __restrict__ Wt,
                         ushort_t* __restrict__ WdT, ushort_t* __restrict__ WtT,
                         const float* __restrict__ bi, const float* __restrict__ bt,
                         float* __restrict__ bd,
                         const float* __restrict__ Wo, const float* __restrict__ Wg,
                         ushort_t* __restrict__ WoT, ushort_t* __restrict__ WgT)
{
    __shared__ float t1[32][33], t2[32][33];
    int bid = blockIdx.x;
    const int tid = threadIdx.x;
    if (bid < 16384) {                       // fp32 -> bf16 convert
        long i = ((long)bid * 256 + tid) * 8;
        float4 a = *(const float4*)(x + i);
        float4 b = *(const float4*)(x + i + 4);
        ushort8 o;
        o[0] = f2bf(a.x); o[1] = f2bf(a.y); o[2] = f2bf(a.z); o[3] = f2bf(a.w);
        o[4] = f2bf(b.x); o[5] = f2bf(b.y); o[6] = f2bf(b.z); o[7] = f2bf(b.w);
        *(ushort8*)(xb + i) = o;
        return;
    }
    bid -= 16384;
    const int tx = tid & 31, ty = tid >> 5;
    if (bid < 1024) {                        // WdT / WtT / bd
        if (bid == 0)
            for (int i = tid; i < ID; i += 256) bd[i] = bi[i] - bt[i];
        int r0 = (bid >> 5) * 32, c0 = (bid & 31) * 32;
        for (int i = ty; i < 32; i += 8) {
            t1[i][tx] = Wi[(long)(r0 + i) * ID + c0 + tx];
            t2[i][tx] = Wt[(long)(r0 + i) * ID + c0 + tx];
        }
        __syncthreads();
        for (int i = ty; i < 32; i += 8) {
            float wi = t1[tx][i], wt = t2[tx][i];
            WdT[(long)(c0 + i) * HD + r0 + tx] = f2bf(wi - wt);
            WtT[(long)(c0 + i) * HD + r0 + tx] = f2bf(wt);
        }
        return;
    }
    bid -= 1024;                             // 3 weight transposes
    int z = bid >> 10, tile = bid & 1023;
    const float* in; ushort_t* outp; int ldo;
    if (z == 0)      { in = Wo;                 outp = WoT;      ldo = ID; }
    else if (z == 1) { in = Wg;                 outp = WgT;      ldo = 2 * HD; }
    else             { in = Wg + (long)HD * HD; outp = WgT + HD; ldo = 2 * HD; }
    int r0 = (tile >> 5) * 32, c0 = (tile & 31) * 32;
    for (int i = ty; i < 32; i += 8)
        t1[i][tx] = in[(long)(r0 + i) * HD + c0 + tx];
    __syncthreads();
    for (int i = ty; i < 32; i += 8)
        outp[(long)(c0 + i) * ldo + r0 + tx] = f2bf(t1[tx][i]);
}

// ---------- bf16 MFMA GEMM: C = alpha*(A @ Bt^T) + add0 + bias [+ C] ----------
// A = [A0 | A1] two optional K-segments (each KSEG wide), bf16 row-major.
// Bt [N, Ktot] bf16 row-major. C fp32 or bf16 (fl&1).
// fl&2: skip tiles N0>M0. fl&4: accumulate into f32 C (RMW).
// fl&8: M-valid = 64 (upper waves skip stores).
// flags&16: DUAL mode — blockIdx.z==1 selects {Bt2, Cv2, bias2, flags2}; z-batch offsets = 0.
// 128x128 tile, BK=32, 4 waves each 64x64 via 4x4 mfma_f32_16x16x32_bf16.
__global__ __launch_bounds__(256, 3) void gemm_bf16(
    const ushort_t* __restrict__ A0, long sA0, int lda0,
    const ushort_t* __restrict__ A1, long sA1, int lda1,
    const ushort_t* __restrict__ Bt, long sBb, int ldb,
    void* __restrict__ Cv, long sCb, int ldc,
    int KSEG, const float* __restrict__ bias,
    float alpha, float add0, int flags,
    const ushort_t* __restrict__ Bt2, void* __restrict__ Cv2,
    const float* __restrict__ bias2, int flags2)
{
    long zb = blockIdx.z;
    int fl = flags;
    if (flags & 16) {
        zb = 0;
        if (blockIdx.z == 1) { Bt = Bt2; Cv = Cv2; bias = bias2; fl = flags2; }
    }
    int bx, by;
    {
        int L = blockIdx.y * gridDim.x + blockIdx.x;
        if ((gridDim.y & 7) == 0) {
            int xcd = L & 7, g = L >> 3;
            bx = g % gridDim.x;
            by = (g / gridDim.x) * 8 + xcd;
        } else { bx = blockIdx.x; by = blockIdx.y; }
    }
    const int M0 = by * 128, N0 = bx * 128;
    if ((fl & 2) && N0 > M0) return;

    __shared__ ushort_t As[128 * 32];
    __shared__ ushort_t Bs[128 * 32];
    const int tid = threadIdx.x;
    const int wave = tid >> 6, lane = tid & 63;
    const int lr = lane & 15, lq = lane >> 4;
    const int wm = (wave & 1) * 64, wn = (wave >> 1) * 64;

    ushort_t* la0 = &As[(wave * 16)      * 32];
    ushort_t* la1 = &As[(wave * 16 + 64) * 32];
    ushort_t* lb0 = &Bs[(wave * 16)      * 32];
    ushort_t* lb1 = &Bs[(wave * 16 + 64) * 32];

    const ushort_t* gb0 = Bt + zb * sBb
                        + (long)(N0 + wave * 16 + (lane >> 2)) * ldb + (lane & 3) * 8;
    const ushort_t* gb1 = gb0 + 64L * ldb;

    floatx4 acc[4][4] = {};

    for (int seg = 0; seg < 2; ++seg) {
        const ushort_t* Ag = (seg == 0) ? A0 : A1;
        if (!Ag) break;
        const int lda = (seg == 0) ? lda0 : lda1;
        Ag += zb * ((seg == 0) ? sA0 : sA1);
        const ushort_t* ga0 = Ag + (long)(M0 + wave * 16 + (lane >> 2)) * lda + (lane & 3) * 8;
        const ushort_t* ga1 = ga0 + 64L * lda;

        for (int k0 = 0; k0 < KSEG; k0 += 32) {
            load_lds16(ga0, la0);
            load_lds16(ga1, la1);
            load_lds16(gb0, lb0);
            load_lds16(gb1, lb1);
            ga0 += 32; ga1 += 32; gb0 += 32; gb1 += 32;
            __syncthreads();
            short8 af[4], bf4[4];
#pragma unroll
            for (int i = 0; i < 4; ++i)
                af[i] = *(const short8*)&As[(wm + i * 16 + lr) * 32 + lq * 8];
#pragma unroll
            for (int j = 0; j < 4; ++j)
                bf4[j] = *(const short8*)&Bs[(wn + j * 16 + lr) * 32 + lq * 8];
#pragma unroll
            for (int i = 0; i < 4; ++i)
#pragma unroll
                for (int j = 0; j < 4; ++j)
                    acc[i][j] = __builtin_amdgcn_mfma_f32_16x16x32_bf16(
                        af[i], bf4[j], acc[i][j], 0, 0, 0);
            __syncthreads();
        }
    }

    // C/D layout: col = lane&15, row = (lane>>4)*4 + reg
    float bv[4] = {0.f, 0.f, 0.f, 0.f};
    if (bias) {
#pragma unroll
        for (int j = 0; j < 4; ++j) bv[j] = bias[N0 + wn + j * 16 + lr];
    }
    if (fl & 1) {
        ushort_t* C = (ushort_t*)Cv + zb * sCb;
#pragma unroll
        for (int i = 0; i < 4; ++i)
#pragma unroll
            for (int r = 0; r < 4; ++r) {
                int row = M0 + wm + i * 16 + lq * 4 + r;
                ushort_t* cp = C + (long)row * ldc + N0 + wn + lr;
#pragma unroll
                for (int j = 0; j < 4; ++j)
                    cp[j * 16] = f2bf(alpha * acc[i][j][r] + add0 + bv[j]);
            }
    } else {
        if ((fl & 8) && wm) return;
        float* C = (float*)Cv + zb * sCb;
#pragma unroll
        for (int i = 0; i < 4; ++i)
#pragma unroll
            for (int r = 0; r < 4; ++r) {
                int row = M0 + wm + i * 16 + lq * 4 + r;
                float* cp = C + (long)row * ldc + N0 + wn + lr;
#pragma unroll
                for (int j = 0; j < 4; ++j) {
                    float val = alpha * acc[i][j][r] + add0 + bv[j];
                    if (fl & 4) val += cp[j * 16];
                    cp[j * 16] = val;
                }
            }
    }
}

// ---------- single-launch blocked solve: all 8 chunks, block-local dependency ----------
// Grid (4, 1, BATCH) = 256 blocks (1/CU). Block (j0,b) owns columns j0..j0+255 of batch b.
// Cross-chunk dependency is block-local: chunk c's MFMA update reads EbT rows
// j0..j0+255 — written by THIS block at earlier chunks. Loop-top __syncthreads
// (compiler drains vmcnt before s_barrier) orders each chunk's EbT stores before
// the next chunk's global_load_lds reads; every EbT element is written exactly
// once (no stale L1), same CU throughout.
// Per chunk: [c>0: acc = G[rows,0:K] @ E_prev; Us = u - acc] | [c==0: Us = u]
//            -> register recurrence on Us -> EbT (c<7) -> fused silu into tgtb.
__global__ __launch_bounds__(256) void solve_all(const float* __restrict__ u,
                                                 const ushort_t* __restrict__ gram,
                                                 ushort_t* __restrict__ ebt,
                                                 ushort_t* __restrict__ tgtb)
{
    const int b = blockIdx.z;
    const int j0 = blockIdx.x << 8;          // 0,256,512,768
    const int tid = threadIdx.x;
    const int wave = tid >> 6, lane = tid & 63;
    const int lr = lane & 15, lq = lane >> 4;

    __shared__ float Us[64][260];                       // 65 KB slab (stride 260: bank-rotate)
    __shared__ __align__(16) char smem2[4096 + 16384];  // As 4KB | Bs 16KB ; reused as Gs 16KB
    ushort_t* As = (ushort_t*)smem2;
    ushort_t* Bs = (ushort_t*)(smem2 + 4096);
    float* Gs = (float*)smem2;

    const ushort_t* Gbase = gram + (long)b * SEQ * SEQ;
    const float* Ubase = u + (long)b * SEQ * ID;
    ushort_t* Eb = ebt + (long)b * ID * SEQ;            // ID x SEQ transposed E
    ushort_t* Tbase = tgtb + (long)b * SEQ * ID;

    for (int c = 0; c < NCHUNK; ++c) {
        const int t0 = c << 6;
        const ushort_t* Gb = Gbase + (long)t0 * SEQ;    // 64 x SEQ chunk rows
        const float* Ub = Ubase + (long)t0 * ID;        // 64 x ID chunk slab

        __syncthreads();   // prior-chunk LDS reads done; EbT stores drained (vmcnt0)

        if (c > 0) {
            const int K = c << 6;
            floatx4 acc[4][4] = {};
            const ushort_t* ga = Gb + (long)(wave * 16 + (lane >> 2)) * SEQ + (lane & 3) * 8;
            const ushort_t* gb = Eb + (long)(j0 + wave * 16 + (lane >> 2)) * SEQ + (lane & 3) * 8;
            ushort_t* la  = &As[(wave * 16) * 32];
            ushort_t* lb0 = &Bs[(wave * 16)       * 32];
            ushort_t* lb1 = &Bs[(64  + wave * 16) * 32];
            ushort_t* lb2 = &Bs[(128 + wave * 16) * 32];
            ushort_t* lb3 = &Bs[(192 + wave * 16) * 32];
            for (int k0 = 0; k0 < K; k0 += 32) {
                load_lds16(ga, la);
                load_lds16(gb,              lb0);
                load_lds16(gb + 64L * SEQ,  lb1);
                load_lds16(gb + 128L * SEQ, lb2);
                load_lds16(gb + 192L * SEQ, lb3);
                ga += 32; gb += 32;
                __syncthreads();
                short8 af[4], bf4[4];
#pragma unroll
                for (int i = 0; i < 4; ++i)
                    af[i] = *(const short8*)&As[(i * 16 + lr) * 32 + lq * 8];
#pragma unroll
                for (int j = 0; j < 4; ++j)
                    bf4[j] = *(const short8*)&Bs[(wave * 64 + j * 16 + lr) * 32 + lq * 8];
#pragma unroll
                for (int i = 0; i < 4; ++i)
#pragma unroll
                    for (int j = 0; j < 4; ++j)
                        acc[i][j] = __builtin_amdgcn_mfma_f32_16x16x32_bf16(
                            af[i], bf4[j], acc[i][j], 0, 0, 0);
                __syncthreads();
            }
            // Us = u_slab - acc   (C/D layout: col=lane&15, row=lq*4+reg)
#pragma unroll
            for (int i = 0; i < 4; ++i)
#pragma unroll
                for (int r = 0; r < 4; ++r) {
                    int row = i * 16 + lq * 4 + r;
                    const float* up = Ub + (long)row * ID + j0 + wave * 64 + lr;
#pragma unroll
                    for (int j = 0; j < 4; ++j)
                        Us[row][wave * 64 + j * 16 + lr] = up[j * 16] - acc[i][j][r];
                }
        } else {
            // plain cooperative slab load
            for (int idx = tid; idx < 64 * 64; idx += 256) {
                int row = idx >> 6, col4 = (idx & 63) << 2;
                float4 v = *(const float4*)(Ub + (long)row * ID + j0 + col4);
                Us[row][col4 + 0] = v.x; Us[row][col4 + 1] = v.y;
                Us[row][col4 + 2] = v.z; Us[row][col4 + 3] = v.w;
            }
        }

        // stage G diag block (bf16 -> f32 LDS; overlays As/Bs — past last read)
        for (int v = tid; v < 512; v += 256) {
            int row = v >> 3, col8 = (v & 7) << 3;
            ushort8 g8 = *(const ushort8*)(Gb + (long)row * SEQ + t0 + col8);
#pragma unroll
            for (int k = 0; k < 8; ++k) Gs[row * 64 + col8 + k] = bf2f(g8[k]);
        }
        __syncthreads();   // Us complete (all waves) + Gs complete

        // intra-chunk forward substitution, one column per thread (all LDS)
        float e[64];
        e[0] = Us[0][tid];
#pragma unroll
        for (int t = 1; t < 64; ++t) {
            float v = Us[t][tid];
            float p0 = 0.f, p1 = 0.f, p2 = 0.f, p3 = 0.f;   // 4-way ILP on the chain
#pragma unroll
            for (int s = 0; s + 3 < t; s += 4) {
                p0 = fmaf(Gs[t * 64 + s + 0], e[s + 0], p0);
                p1 = fmaf(Gs[t * 64 + s + 1], e[s + 1], p1);
                p2 = fmaf(Gs[t * 64 + s + 2], e[s + 2], p2);
                p3 = fmaf(Gs[t * 64 + s + 3], e[s + 3], p3);
            }
#pragma unroll
            for (int s = t & ~3; s < t; ++s)
                p0 = fmaf(Gs[t * 64 + s], e[s], p0);
            e[t] = v - ((p0 + p1) + (p2 + p3));
        }

        // transposed bf16 copy for later chunks' MFMA updates
        if (c < NCHUNK - 1) {
            ushort_t* EB = Eb + (long)(j0 + tid) * SEQ + t0;
#pragma unroll
            for (int g = 0; g < 8; ++g) {
                ushort8 o;
#pragma unroll
                for (int k = 0; k < 8; ++k) o[k] = f2bf(e[g * 8 + k]);
                *(ushort8*)(EB + g * 8) = o;
            }
        }

        // fused silu, in place over tgtb (tgtb becomes hb)
        ushort_t* Tp = Tbase + (long)t0 * ID + j0 + tid;
#pragma unroll
        for (int t = 0; t < 64; ++t) {
            float v = e[t] + bf2f(Tp[(long)t * ID]);
            Tp[(long)t * ID] = f2bf(v / (1.0f + __expf(-v)));
        }
    }
}

// ---------- gate + residual mix + LayerNorm (z, ttt in bf16) ----------
__global__ __launch_bounds__(256) void gate_ln(
    const ushort_t* __restrict__ zb, const ushort_t* __restrict__ tttb,
    const float* __restrict__ x, const float* __restrict__ gamma,
    const float* __restrict__ bet, float* __restrict__ out)
{
    long base = (long)blockIdx.x * HD + threadIdx.x * 4;
    ushort4v zv4 = *(const ushort4v*)(zb + base);
    ushort4v tv4 = *(const ushort4v*)(tttb + base);
    float4 xv = *(const float4*)(x + base);
    float xr[4] = {xv.x, xv.y, xv.z, xv.w};
    float y[4];
#pragma unroll
    for (int k = 0; k < 4; ++k) {
        float g = 1.0f / (1.0f + __expf(-bf2f(zv4[k])));
        float t = bf2f(tv4[k]);
        y[k] = g * t + (1.0f - g) * xr[k];
    }
    float sum = y[0] + y[1] + y[2] + y[3];
    float sq  = y[0]*y[0] + y[1]*y[1] + y[2]*y[2] + y[3]*y[3];
#pragma unroll
    for (int off = 32; off > 0; off >>= 1) {
        sum += __shfl_down(sum, off);
        sq  += __shfl_down(sq, off);
    }
    __shared__ float s1[4], s2[4];
    int wid = threadIdx.x >> 6;
    if ((threadIdx.x & 63) == 0) { s1[wid] = sum; s2[wid] = sq; }
    __syncthreads();
    float tot = s1[0] + s1[1] + s1[2] + s1[3];
    float tsq = s2[0] + s2[1] + s2[2] + s2[3];
    float mu = tot * (1.0f / HD);
    float var = tsq * (1.0f / HD) - mu * mu;
    float rs = rsqrtf(var + 1e-5f);
    int col = threadIdx.x * 4;
    float4 ov;
    ov.x = (y[0] - mu) * rs * gamma[col + 0] + bet[col + 0];
    ov.y = (y[1] - mu) * rs * gamma[col + 1] + bet[col + 1];
    ov.z = (y[2] - mu) * rs * gamma[col + 2] + bet[col + 2];
    ov.w = (y[3] - mu) * rs * gamma[col + 3] + bet[col + 3];
    *(float4*)(out + base) = ov;
}

extern "C" void kernel_launch(void* const* d_in, const int* in_sizes, int n_in,
                              void* d_out, int out_size, void* d_ws, size_t ws_size,
                              hipStream_t stream)
{
    const float* x    = (const float*)d_in[0];
    const float* Wi   = (const float*)d_in[1];
    const float* bi   = (const float*)d_in[2];
    const float* Wt   = (const float*)d_in[3];
    const float* bt   = (const float*)d_in[4];
    const float* Wo   = (const float*)d_in[5];
    const float* bo   = (const float*)d_in[6];
    const float* Wg   = (const float*)d_in[7];
    const float* bg   = (const float*)d_in[8];
    const float* gam  = (const float*)d_in[9];
    const float* bet  = (const float*)d_in[10];
    float* out = (float*)d_out;

    // Workspace ~394 MB (unchanged footprint):
    //   u    [BS,ID] f32 128MB : RHS (read-only during solve); AFTER solve reused as zb bf16
    //   tgtb [BS,ID] bf16 64MB : target; solve_all silu-rewrites IN PLACE -> becomes hb
    //   gram region       64MB : gramb bf16 [B,S,S] (32MB); dead after solve
    //   xb   [BS,HD] bf16 64MB : x bf16 (live until z GEMM)
    //   tttb [BS,HD] bf16 64MB : DURING solve overlaid by EbT bf16 [B,ID,SEQ]; after: ttt
    //   weights bf16 ~10MB + bd
    float* u       = (float*)d_ws;
    ushort_t* tgtb = (ushort_t*)(u + (long)BS * ID);
    float* gram    = (float*)(tgtb + (long)BS * ID);
    ushort_t* xb   = (ushort_t*)(gram + (long)BATCH * SEQ * SEQ);
    ushort_t* tttb = xb + (long)BS * HD;
    ushort_t* WdT  = tttb + (long)BS * HD;            // [ID,HD]
    ushort_t* WtT  = WdT + (long)HD * ID;             // [ID,HD]
    ushort_t* WoT  = WtT + (long)HD * ID;             // [HD,ID]
    ushort_t* WgT  = WoT + (long)HD * ID;             // [HD, 2*HD] concat K
    float* bd      = (float*)(WgT + (long)HD * 2 * HD);
    ushort_t* gramb = (ushort_t*)gram;                // gram stored bf16
    ushort_t* ebt   = (ushort_t*)tttb;                // overlay: EbT during solve
    ushort_t* hb    = tgtb;                           // after solve: silu output in place
    ushort_t* zb    = (ushort_t*)u;                   // overlay: after solve

    // ---- prep (1 launch: convert + prep_w + 3 transposes) ----
    prep_all<<<16384 + 1024 + 3072, 256, 0, stream>>>(
        x, xb, Wi, Wt, WdT, WtT, bi, bt, bd, Wo, Wg, WoT, WgT);

    dim3 gBig(ID / 128, BS / 128, 1);   // 8 x 256
    // DUAL: z=0: u = x @ (Wi - Wt) + (bi - bt) [f32]; z=1: target = x @ Wt + bt [bf16]
    gemm_bf16<<<dim3(ID / 128, BS / 128, 2), 256, 0, stream>>>(
        xb, 0, HD, nullptr, 0, 0, WdT, 0, HD,
        u, 0, ID, HD, bd, 1.f, 0.f, 16,
        WtT, tgtb, bt, 1);
    // gram = (LR/I) * (X X^T + 1)     [bf16 out, lower tiles only]
    gemm_bf16<<<dim3(SEQ / 128, SEQ / 128, BATCH), 256, 0, stream>>>(
        xb, (long)SEQ * HD, HD, nullptr, 0, 0, xb, (long)SEQ * HD, HD,
        gramb, (long)SEQ * SEQ, SEQ, HD, nullptr, LR_OVER_I, LR_OVER_I, 2 | 1,
        nullptr, nullptr, nullptr, 0);

    // ---- blocked forward substitution + fused silu (ONE launch, 8 chunks in-kernel) ----
    solve_all<<<dim3(4, 1, BATCH), 256, 0, stream>>>(u, gramb, ebt, tgtb);

    // ttt = h @ Wo + bo               [bf16 out; hb == tgtb in place]
    gemm_bf16<<<gBig, 256, 0, stream>>>(hb, 0, ID, nullptr, 0, 0, WoT, 0, ID,
                                        tttb, 0, HD, ID, bo, 1.f, 0.f, 1,
                                        nullptr, nullptr, nullptr, 0);
    // z = [x, ttt] @ Wg + bg          [bf16 out, two K-segments; zb overlays u]
    gemm_bf16<<<gBig, 256, 0, stream>>>(xb, 0, HD, tttb, 0, HD, WgT, 0, 2 * HD,
                                        zb, 0, HD, HD, bg, 1.f, 0.f, 1,
                                        nullptr, nullptr, nullptr, 0);
    // out = LN(g*ttt + (1-g)*x)
    gate_ln<<<BS, 256, 0, stream>>>(zb, tttb, x, gam, bet, out);
}

// Round 6
// 1046.930 us; speedup vs baseline: 1.1703x; 1.1703x over previous
//
#include <hip/hip_runtime.h>

#define HD 1024
#define ID 1024
#define BATCH 64
#define SEQ 512
#define BS (BATCH*SEQ)     // 32768 rows
#define CHUNK 64
#define NCHUNK (SEQ/CHUNK) // 8
#define LR_OVER_I (0.01f/1024.0f)

typedef unsigned int u32;
typedef unsigned short ushort_t;
typedef __attribute__((ext_vector_type(8))) short short8;        // 8 bf16 (4 VGPRs)
typedef __attribute__((ext_vector_type(8))) unsigned short ushort8;
typedef __attribute__((ext_vector_type(4))) unsigned short ushort4v;
typedef __attribute__((ext_vector_type(4))) float floatx4;

__device__ inline ushort_t f2bf(float f) {
    union { float f; u32 u; } v; v.f = f;
    return (ushort_t)((v.u + 0x7FFFu + ((v.u >> 16) & 1u)) >> 16);  // RNE
}
__device__ inline float bf2f(ushort_t h) {
    union { u32 u; float f; } v; v.u = ((u32)h) << 16; return v.f;
}

__device__ inline void load_lds16(const void* g, void* l) {
    __builtin_amdgcn_global_load_lds(
        (const __attribute__((address_space(1))) u32*)g,
        (__attribute__((address_space(3))) u32*)l, 16, 0, 0);
}

// ---------- merged prep: convert x->bf16 | WdT/WtT/bd | 3 weight transposes ----------
// grid: [0,16384) convert; [16384,17408) prep_w tiles; [17408,20480) transposes.
__global__ void prep_all(const float* __restrict__ x, ushort_t* __restrict__ xb,
                         const float* __restrict__ Wi, const float* __restrict__ Wt,
                         ushort_t* __restrict__ WdT, ushort_t* __restrict__ WtT,
                         const float* __restrict__ bi, const float* __restrict__ bt,
                         float* __restrict__ bd,
                         const float* __restrict__ Wo, const float* __restrict__ Wg,
                         ushort_t* __restrict__ WoT, ushort_t* __restrict__ WgT)
{
    __shared__ float t1[32][33], t2[32][33];
    int bid = blockIdx.x;
    const int tid = threadIdx.x;
    if (bid < 16384) {                       // fp32 -> bf16 convert
        long i = ((long)bid * 256 + tid) * 8;
        float4 a = *(const float4*)(x + i);
        float4 b = *(const float4*)(x + i + 4);
        ushort8 o;
        o[0] = f2bf(a.x); o[1] = f2bf(a.y); o[2] = f2bf(a.z); o[3] = f2bf(a.w);
        o[4] = f2bf(b.x); o[5] = f2bf(b.y); o[6] = f2bf(b.z); o[7] = f2bf(b.w);
        *(ushort8*)(xb + i) = o;
        return;
    }
    bid -= 16384;
    const int tx = tid & 31, ty = tid >> 5;
    if (bid < 1024) {                        // WdT / WtT / bd
        if (bid == 0)
            for (int i = tid; i < ID; i += 256) bd[i] = bi[i] - bt[i];
        int r0 = (bid >> 5) * 32, c0 = (bid & 31) * 32;
        for (int i = ty; i < 32; i += 8) {
            t1[i][tx] = Wi[(long)(r0 + i) * ID + c0 + tx];
            t2[i][tx] = Wt[(long)(r0 + i) * ID + c0 + tx];
        }
        __syncthreads();
        for (int i = ty; i < 32; i += 8) {
            float wi = t1[tx][i], wt = t2[tx][i];
            WdT[(long)(c0 + i) * HD + r0 + tx] = f2bf(wi - wt);
            WtT[(long)(c0 + i) * HD + r0 + tx] = f2bf(wt);
        }
        return;
    }
    bid -= 1024;                             // 3 weight transposes
    int z = bid >> 10, tile = bid & 1023;
    const float* in; ushort_t* outp; int ldo;
    if (z == 0)      { in = Wo;                 outp = WoT;      ldo = ID; }
    else if (z == 1) { in = Wg;                 outp = WgT;      ldo = 2 * HD; }
    else             { in = Wg + (long)HD * HD; outp = WgT + HD; ldo = 2 * HD; }
    int r0 = (tile >> 5) * 32, c0 = (tile & 31) * 32;
    for (int i = ty; i < 32; i += 8)
        t1[i][tx] = in[(long)(r0 + i) * HD + c0 + tx];
    __syncthreads();
    for (int i = ty; i < 32; i += 8)
        outp[(long)(c0 + i) * ldo + r0 + tx] = f2bf(t1[tx][i]);
}

// ---------- bf16 MFMA GEMM: C = alpha*(A @ Bt^T) + add0 + bias [+ C] ----------
// A = [A0 | A1] two optional K-segments (each KSEG wide), bf16 row-major.
// Bt [N, Ktot] bf16 row-major. C fp32 or bf16 (fl&1).
// fl&2: skip tiles N0>M0. fl&4: accumulate into f32 C (RMW).
// fl&8: M-valid = 64 (upper waves skip stores).
// flags&16: DUAL mode — blockIdx.z==1 selects {Bt2, Cv2, bias2, flags2}; z-batch offsets = 0.
// 128x128 tile, BK=32, 4 waves each 64x64 via 4x4 mfma_f32_16x16x32_bf16.
__global__ __launch_bounds__(256, 3) void gemm_bf16(
    const ushort_t* __restrict__ A0, long sA0, int lda0,
    const ushort_t* __restrict__ A1, long sA1, int lda1,
    const ushort_t* __restrict__ Bt, long sBb, int ldb,
    void* __restrict__ Cv, long sCb, int ldc,
    int KSEG, const float* __restrict__ bias,
    float alpha, float add0, int flags,
    const ushort_t* __restrict__ Bt2, void* __restrict__ Cv2,
    const float* __restrict__ bias2, int flags2)
{
    long zb = blockIdx.z;
    int fl = flags;
    if (flags & 16) {
        zb = 0;
        if (blockIdx.z == 1) { Bt = Bt2; Cv = Cv2; bias = bias2; fl = flags2; }
    }
    int bx, by;
    {
        int L = blockIdx.y * gridDim.x + blockIdx.x;
        if ((gridDim.y & 7) == 0) {
            int xcd = L & 7, g = L >> 3;
            bx = g % gridDim.x;
            by = (g / gridDim.x) * 8 + xcd;
        } else { bx = blockIdx.x; by = blockIdx.y; }
    }
    const int M0 = by * 128, N0 = bx * 128;
    if ((fl & 2) && N0 > M0) return;

    __shared__ ushort_t As[128 * 32];
    __shared__ ushort_t Bs[128 * 32];
    const int tid = threadIdx.x;
    const int wave = tid >> 6, lane = tid & 63;
    const int lr = lane & 15, lq = lane >> 4;
    const int wm = (wave & 1) * 64, wn = (wave >> 1) * 64;

    ushort_t* la0 = &As[(wave * 16)      * 32];
    ushort_t* la1 = &As[(wave * 16 + 64) * 32];
    ushort_t* lb0 = &Bs[(wave * 16)      * 32];
    ushort_t* lb1 = &Bs[(wave * 16 + 64) * 32];

    const ushort_t* gb0 = Bt + zb * sBb
                        + (long)(N0 + wave * 16 + (lane >> 2)) * ldb + (lane & 3) * 8;
    const ushort_t* gb1 = gb0 + 64L * ldb;

    floatx4 acc[4][4] = {};

    for (int seg = 0; seg < 2; ++seg) {
        const ushort_t* Ag = (seg == 0) ? A0 : A1;
        if (!Ag) break;
        const int lda = (seg == 0) ? lda0 : lda1;
        Ag += zb * ((seg == 0) ? sA0 : sA1);
        const ushort_t* ga0 = Ag + (long)(M0 + wave * 16 + (lane >> 2)) * lda + (lane & 3) * 8;
        const ushort_t* ga1 = ga0 + 64L * lda;

        for (int k0 = 0; k0 < KSEG; k0 += 32) {
            load_lds16(ga0, la0);
            load_lds16(ga1, la1);
            load_lds16(gb0, lb0);
            load_lds16(gb1, lb1);
            ga0 += 32; ga1 += 32; gb0 += 32; gb1 += 32;
            __syncthreads();
            short8 af[4], bf4[4];
#pragma unroll
            for (int i = 0; i < 4; ++i)
                af[i] = *(const short8*)&As[(wm + i * 16 + lr) * 32 + lq * 8];
#pragma unroll
            for (int j = 0; j < 4; ++j)
                bf4[j] = *(const short8*)&Bs[(wn + j * 16 + lr) * 32 + lq * 8];
#pragma unroll
            for (int i = 0; i < 4; ++i)
#pragma unroll
                for (int j = 0; j < 4; ++j)
                    acc[i][j] = __builtin_amdgcn_mfma_f32_16x16x32_bf16(
                        af[i], bf4[j], acc[i][j], 0, 0, 0);
            __syncthreads();
        }
    }

    // C/D layout: col = lane&15, row = (lane>>4)*4 + reg
    float bv[4] = {0.f, 0.f, 0.f, 0.f};
    if (bias) {
#pragma unroll
        for (int j = 0; j < 4; ++j) bv[j] = bias[N0 + wn + j * 16 + lr];
    }
    if (fl & 1) {
        ushort_t* C = (ushort_t*)Cv + zb * sCb;
#pragma unroll
        for (int i = 0; i < 4; ++i)
#pragma unroll
            for (int r = 0; r < 4; ++r) {
                int row = M0 + wm + i * 16 + lq * 4 + r;
                ushort_t* cp = C + (long)row * ldc + N0 + wn + lr;
#pragma unroll
                for (int j = 0; j < 4; ++j)
                    cp[j * 16] = f2bf(alpha * acc[i][j][r] + add0 + bv[j]);
            }
    } else {
        if ((fl & 8) && wm) return;
        float* C = (float*)Cv + zb * sCb;
#pragma unroll
        for (int i = 0; i < 4; ++i)
#pragma unroll
            for (int r = 0; r < 4; ++r) {
                int row = M0 + wm + i * 16 + lq * 4 + r;
                float* cp = C + (long)row * ldc + N0 + wn + lr;
#pragma unroll
                for (int j = 0; j < 4; ++j) {
                    float val = alpha * acc[i][j][r] + add0 + bv[j];
                    if (fl & 4) val += cp[j * 16];
                    cp[j * 16] = val;
                }
            }
    }
}

// ---------- per-chunk solve (8 launches): MFMA update + intra solve + fused silu ----------
// Grid (4, 1, BATCH), 256 threads. Block owns a 64x256 slab of one batch.
// Latency fixes vs the earlier version:
//  * u-slab prefetched into Us via global_load_lds at kernel entry (rows are 1KB
//    contiguous = wave-uniform-dest pattern); completes under the first staging
//    barrier. Epilogue becomes an LDS RMW (no 64 scalar global loads).
//  * K-loop staging is 2-phase double-buffered (T3-min template): issue next
//    step's loads BEFORE current step's ds_read+MFMA, ONE barrier per step.
__global__ __launch_bounds__(256) void solve_chunk(const float* __restrict__ u,
                                                   const ushort_t* __restrict__ gram,
                                                   ushort_t* __restrict__ ebt,
                                                   ushort_t* __restrict__ tgtb, int c)
{
    const int b = blockIdx.z;
    const int j0 = blockIdx.x << 8;          // 0,256,512,768
    const int t0 = c << 6;
    const int tid = threadIdx.x;
    const int wave = tid >> 6, lane = tid & 63;
    const int lr = lane & 15, lq = lane >> 4;

    __shared__ float Us[64][260];                        // 66.5 KB slab (stride 260)
    __shared__ __align__(16) char smem2[2][20480];       // 2 x (As 4KB | Bs 16KB)
    float* Gs = (float*)smem2;                           // 16 KB overlay (post-loop)

    const ushort_t* Gb = gram + (long)b * SEQ * SEQ + (long)t0 * SEQ;   // 64 x SEQ
    const float* Ub = u + (long)b * SEQ * ID + (long)t0 * ID;           // 64 x ID
    ushort_t* Eb = ebt + (long)b * ID * SEQ;                            // ID x SEQ

    // ---- u-slab prefetch: one row (1KB) per issue, 16B/lane; wave w owns rows w*16..+15
    {
        const int r0w = wave * 16;
#pragma unroll
        for (int r = 0; r < 16; ++r)
            load_lds16(Ub + (long)(r0w + r) * ID + j0 + (lane << 2), &Us[r0w + r][0]);
    }

    if (c > 0) {
        const int K = c << 6;
        floatx4 acc[4][4] = {};
        const int arow = wave * 16 + (lane >> 2);
        const int acol = (lane & 3) * 8;

        auto stage = [&](int bsel, int k0) {
            ushort_t* As_ = (ushort_t*)smem2[bsel];
            ushort_t* Bs_ = (ushort_t*)(smem2[bsel] + 4096);
            const ushort_t* ga = Gb + (long)arow * SEQ + acol + k0;
            const ushort_t* gb = Eb + (long)(j0 + arow) * SEQ + acol + k0;
            load_lds16(ga,               &As_[(wave * 16) * 32]);
            load_lds16(gb,               &Bs_[(wave * 16)       * 32]);
            load_lds16(gb + 64L * SEQ,   &Bs_[(64  + wave * 16) * 32]);
            load_lds16(gb + 128L * SEQ,  &Bs_[(128 + wave * 16) * 32]);
            load_lds16(gb + 192L * SEQ,  &Bs_[(192 + wave * 16) * 32]);
        };

        stage(0, 0);
        __syncthreads();                     // buf0 ready (also drains u-prefetch)
        int buf = 0;
        for (int k0 = 0; k0 < K; k0 += 32) {
            if (k0 + 32 < K) stage(buf ^ 1, k0 + 32);   // issue next BEFORE compute
            const ushort_t* As_ = (const ushort_t*)smem2[buf];
            const ushort_t* Bs_ = (const ushort_t*)(smem2[buf] + 4096);
            short8 af[4], bf4[4];
#pragma unroll
            for (int i = 0; i < 4; ++i)
                af[i] = *(const short8*)&As_[(i * 16 + lr) * 32 + lq * 8];
#pragma unroll
            for (int j = 0; j < 4; ++j)
                bf4[j] = *(const short8*)&Bs_[(wave * 64 + j * 16 + lr) * 32 + lq * 8];
#pragma unroll
            for (int i = 0; i < 4; ++i)
#pragma unroll
                for (int j = 0; j < 4; ++j)
                    acc[i][j] = __builtin_amdgcn_mfma_f32_16x16x32_bf16(
                        af[i], bf4[j], acc[i][j], 0, 0, 0);
            __syncthreads();                 // drains next-stage loads (issued early)
            buf ^= 1;
        }
        // epilogue: Us -= acc  (LDS RMW; u-prefetch drained at first barrier)
        // C/D layout: col=lane&15, row=lq*4+reg
#pragma unroll
        for (int i = 0; i < 4; ++i)
#pragma unroll
            for (int r = 0; r < 4; ++r) {
                int row = i * 16 + lq * 4 + r;
#pragma unroll
                for (int j = 0; j < 4; ++j)
                    Us[row][wave * 64 + j * 16 + lr] -= acc[i][j][r];
            }
    }

    // stage G diag block (bf16 -> f32 LDS; overlays As/Bs — past last read+barrier)
    for (int v = tid; v < 512; v += 256) {
        int row = v >> 3, col8 = (v & 7) << 3;
        ushort8 g8 = *(const ushort8*)(Gb + (long)row * SEQ + t0 + col8);
#pragma unroll
        for (int k = 0; k < 8; ++k) Gs[row * 64 + col8 + k] = bf2f(g8[k]);
    }
    __syncthreads();   // Us (prefetch +/- acc) complete, Gs complete (drains vmcnt)

    // intra-chunk forward substitution, one column per thread (all LDS)
    float e[64];
    e[0] = Us[0][tid];
#pragma unroll
    for (int t = 1; t < 64; ++t) {
        float v = Us[t][tid];
        float p0 = 0.f, p1 = 0.f, p2 = 0.f, p3 = 0.f;   // 4-way ILP on the chain
#pragma unroll
        for (int s = 0; s + 3 < t; s += 4) {
            p0 = fmaf(Gs[t * 64 + s + 0], e[s + 0], p0);
            p1 = fmaf(Gs[t * 64 + s + 1], e[s + 1], p1);
            p2 = fmaf(Gs[t * 64 + s + 2], e[s + 2], p2);
            p3 = fmaf(Gs[t * 64 + s + 3], e[s + 3], p3);
        }
#pragma unroll
        for (int s = t & ~3; s < t; ++s)
            p0 = fmaf(Gs[t * 64 + s], e[s], p0);
        e[t] = v - ((p0 + p1) + (p2 + p3));
    }

    // transposed bf16 copy for later chunks' MFMA updates
    if (c < NCHUNK - 1) {
        ushort_t* EB = Eb + (long)(j0 + tid) * SEQ + t0;
#pragma unroll
        for (int g = 0; g < 8; ++g) {
            ushort8 o;
#pragma unroll
            for (int k = 0; k < 8; ++k) o[k] = f2bf(e[g * 8 + k]);
            *(ushort8*)(EB + g * 8) = o;
        }
    }

    // fused silu, in place over tgtb (tgtb becomes hb); coalesced per wave (128B/row)
    ushort_t* Tp = tgtb + ((long)b * SEQ + t0) * ID + j0 + tid;
#pragma unroll
    for (int t = 0; t < 64; ++t) {
        float v = e[t] + bf2f(Tp[(long)t * ID]);
        Tp[(long)t * ID] = f2bf(v / (1.0f + __expf(-v)));
    }
}

// ---------- gate + residual mix + LayerNorm (z, ttt in bf16) ----------
__global__ __launch_bounds__(256) void gate_ln(
    const ushort_t* __restrict__ zb, const ushort_t* __restrict__ tttb,
    const float* __restrict__ x, const float* __restrict__ gamma,
    const float* __restrict__ bet, float* __restrict__ out)
{
    long base = (long)blockIdx.x * HD + threadIdx.x * 4;
    ushort4v zv4 = *(const ushort4v*)(zb + base);
    ushort4v tv4 = *(const ushort4v*)(tttb + base);
    float4 xv = *(const float4*)(x + base);
    float xr[4] = {xv.x, xv.y, xv.z, xv.w};
    float y[4];
#pragma unroll
    for (int k = 0; k < 4; ++k) {
        float g = 1.0f / (1.0f + __expf(-bf2f(zv4[k])));
        float t = bf2f(tv4[k]);
        y[k] = g * t + (1.0f - g) * xr[k];
    }
    float sum = y[0] + y[1] + y[2] + y[3];
    float sq  = y[0]*y[0] + y[1]*y[1] + y[2]*y[2] + y[3]*y[3];
#pragma unroll
    for (int off = 32; off > 0; off >>= 1) {
        sum += __shfl_down(sum, off);
        sq  += __shfl_down(sq, off);
    }
    __shared__ float s1[4], s2[4];
    int wid = threadIdx.x >> 6;
    if ((threadIdx.x & 63) == 0) { s1[wid] = sum; s2[wid] = sq; }
    __syncthreads();
    float tot = s1[0] + s1[1] + s1[2] + s1[3];
    float tsq = s2[0] + s2[1] + s2[2] + s2[3];
    float mu = tot * (1.0f / HD);
    float var = tsq * (1.0f / HD) - mu * mu;
    float rs = rsqrtf(var + 1e-5f);
    int col = threadIdx.x * 4;
    float4 ov;
    ov.x = (y[0] - mu) * rs * gamma[col + 0] + bet[col + 0];
    ov.y = (y[1] - mu) * rs * gamma[col + 1] + bet[col + 1];
    ov.z = (y[2] - mu) * rs * gamma[col + 2] + bet[col + 2];
    ov.w = (y[3] - mu) * rs * gamma[col + 3] + bet[col + 3];
    *(float4*)(out + base) = ov;
}

extern "C" void kernel_launch(void* const* d_in, const int* in_sizes, int n_in,
                              void* d_out, int out_size, void* d_ws, size_t ws_size,
                              hipStream_t stream)
{
    const float* x    = (const float*)d_in[0];
    const float* Wi   = (const float*)d_in[1];
    const float* bi   = (const float*)d_in[2];
    const float* Wt   = (const float*)d_in[3];
    const float* bt   = (const float*)d_in[4];
    const float* Wo   = (const float*)d_in[5];
    const float* bo   = (const float*)d_in[6];
    const float* Wg   = (const float*)d_in[7];
    const float* bg   = (const float*)d_in[8];
    const float* gam  = (const float*)d_in[9];
    const float* bet  = (const float*)d_in[10];
    float* out = (float*)d_out;

    // Workspace ~394 MB (unchanged footprint):
    //   u    [BS,ID] f32 128MB : RHS (read-only during solve); AFTER solve reused as zb bf16
    //   tgtb [BS,ID] bf16 64MB : target; solve_chunk silu-rewrites IN PLACE -> becomes hb
    //   gram region       64MB : gramb bf16 [B,S,S] (32MB); dead after solve
    //   xb   [BS,HD] bf16 64MB : x bf16 (live until z GEMM)
    //   tttb [BS,HD] bf16 64MB : DURING solve overlaid by EbT bf16 [B,ID,SEQ]; after: ttt
    //   weights bf16 ~10MB + bd
    float* u       = (float*)d_ws;
    ushort_t* tgtb = (ushort_t*)(u + (long)BS * ID);
    float* gram    = (float*)(tgtb + (long)BS * ID);
    ushort_t* xb   = (ushort_t*)(gram + (long)BATCH * SEQ * SEQ);
    ushort_t* tttb = xb + (long)BS * HD;
    ushort_t* WdT  = tttb + (long)BS * HD;            // [ID,HD]
    ushort_t* WtT  = WdT + (long)HD * ID;             // [ID,HD]
    ushort_t* WoT  = WtT + (long)HD * ID;             // [HD,ID]
    ushort_t* WgT  = WoT + (long)HD * ID;             // [HD, 2*HD] concat K
    float* bd      = (float*)(WgT + (long)HD * 2 * HD);
    ushort_t* gramb = (ushort_t*)gram;                // gram stored bf16
    ushort_t* ebt   = (ushort_t*)tttb;                // overlay: EbT during solve
    ushort_t* hb    = tgtb;                           // after solve: silu output in place
    ushort_t* zb    = (ushort_t*)u;                   // overlay: after solve

    // ---- prep (1 launch: convert + prep_w + 3 transposes) ----
    prep_all<<<16384 + 1024 + 3072, 256, 0, stream>>>(
        x, xb, Wi, Wt, WdT, WtT, bi, bt, bd, Wo, Wg, WoT, WgT);

    dim3 gBig(ID / 128, BS / 128, 1);   // 8 x 256
    // DUAL: z=0: u = x @ (Wi - Wt) + (bi - bt) [f32]; z=1: target = x @ Wt + bt [bf16]
    gemm_bf16<<<dim3(ID / 128, BS / 128, 2), 256, 0, stream>>>(
        xb, 0, HD, nullptr, 0, 0, WdT, 0, HD,
        u, 0, ID, HD, bd, 1.f, 0.f, 16,
        WtT, tgtb, bt, 1);
    // gram = (LR/I) * (X X^T + 1)     [bf16 out, lower tiles only]
    gemm_bf16<<<dim3(SEQ / 128, SEQ / 128, BATCH), 256, 0, stream>>>(
        xb, (long)SEQ * HD, HD, nullptr, 0, 0, xb, (long)SEQ * HD, HD,
        gramb, (long)SEQ * SEQ, SEQ, HD, nullptr, LR_OVER_I, LR_OVER_I, 2 | 1,
        nullptr, nullptr, nullptr, 0);

    // ---- blocked forward substitution + fused silu (8 launches, pipelined staging) ----
    for (int c = 0; c < NCHUNK; ++c)
        solve_chunk<<<dim3(4, 1, BATCH), 256, 0, stream>>>(u, gramb, ebt, tgtb, c);

    // ttt = h @ Wo + bo               [bf16 out; hb == tgtb in place]
    gemm_bf16<<<gBig, 256, 0, stream>>>(hb, 0, ID, nullptr, 0, 0, WoT, 0, ID,
                                        tttb, 0, HD, ID, bo, 1.f, 0.f, 1,
                                        nullptr, nullptr, nullptr, 0);
    // z = [x, ttt] @ Wg + bg          [bf16 out, two K-segments; zb overlays u]
    gemm_bf16<<<gBig, 256, 0, stream>>>(xb, 0, HD, tttb, 0, HD, WgT, 0, 2 * HD,
                                        zb, 0, HD, HD, bg, 1.f, 0.f, 1,
                                        nullptr, nullptr, nullptr, 0);
    // out = LN(g*ttt + (1-g)*x)
    gate_ln<<<BS, 256, 0, stream>>>(zb, tttb, x, gam, bet, out);
}

// Round 8
// 1035.003 us; speedup vs baseline: 1.1838x; 1.0115x over previous
//
#include <hip/hip_runtime.h>

#define HD 1024
#define ID 1024
#define BATCH 64
#define SEQ 512
#define BS (BATCH*SEQ)     // 32768 rows
#define CHUNK 64
#define NCHUNK (SEQ/CHUNK) // 8
#define LR_OVER_I (0.01f/1024.0f)

typedef unsigned int u32;
typedef unsigned short ushort_t;
typedef __attribute__((ext_vector_type(8))) short short8;        // 8 bf16 (4 VGPRs)
typedef __attribute__((ext_vector_type(8))) unsigned short ushort8;
typedef __attribute__((ext_vector_type(4))) unsigned short ushort4v;
typedef __attribute__((ext_vector_type(4))) float floatx4;

__device__ inline ushort_t f2bf(float f) {
    union { float f; u32 u; } v; v.f = f;
    return (ushort_t)((v.u + 0x7FFFu + ((v.u >> 16) & 1u)) >> 16);  // RNE
}
__device__ inline float bf2f(ushort_t h) {
    union { u32 u; float f; } v; v.u = ((u32)h) << 16; return v.f;
}

__device__ inline void load_lds16(const void* g, void* l) {
    __builtin_amdgcn_global_load_lds(
        (const __attribute__((address_space(1))) u32*)g,
        (__attribute__((address_space(3))) u32*)l, 16, 0, 0);
}

// ---------- merged prep: convert x->bf16 | WdT/WtT/bd | 3 weight transposes ----------
// grid: [0,16384) convert; [16384,17408) prep_w tiles; [17408,20480) transposes.
__global__ void prep_all(const float* __restrict__ x, ushort_t* __restrict__ xb,
                         const float* __restrict__ Wi, const float* __restrict__ Wt,
                         ushort_t* __restrict__ WdT, ushort_t* __restrict__ WtT,
                         const float* __restrict__ bi, const float* __restrict__ bt,
                         float* __restrict__ bd,
                         const float* __restrict__ Wo, const float* __restrict__ Wg,
                         ushort_t* __restrict__ WoT, ushort_t* __restrict__ WgT)
{
    __shared__ float t1[32][33], t2[32][33];
    int bid = blockIdx.x;
    const int tid = threadIdx.x;
    if (bid < 16384) {                       // fp32 -> bf16 convert
        long i = ((long)bid * 256 + tid) * 8;
        float4 a = *(const float4*)(x + i);
        float4 b = *(const float4*)(x + i + 4);
        ushort8 o;
        o[0] = f2bf(a.x); o[1] = f2bf(a.y); o[2] = f2bf(a.z); o[3] = f2bf(a.w);
        o[4] = f2bf(b.x); o[5] = f2bf(b.y); o[6] = f2bf(b.z); o[7] = f2bf(b.w);
        *(ushort8*)(xb + i) = o;
        return;
    }
    bid -= 16384;
    const int tx = tid & 31, ty = tid >> 5;
    if (bid < 1024) {                        // WdT / WtT / bd
        if (bid == 0)
            for (int i = tid; i < ID; i += 256) bd[i] = bi[i] - bt[i];
        int r0 = (bid >> 5) * 32, c0 = (bid & 31) * 32;
        for (int i = ty; i < 32; i += 8) {
            t1[i][tx] = Wi[(long)(r0 + i) * ID + c0 + tx];
            t2[i][tx] = Wt[(long)(r0 + i) * ID + c0 + tx];
        }
        __syncthreads();
        for (int i = ty; i < 32; i += 8) {
            float wi = t1[tx][i], wt = t2[tx][i];
            WdT[(long)(c0 + i) * HD + r0 + tx] = f2bf(wi - wt);
            WtT[(long)(c0 + i) * HD + r0 + tx] = f2bf(wt);
        }
        return;
    }
    bid -= 1024;                             // 3 weight transposes
    int z = bid >> 10, tile = bid & 1023;
    const float* in; ushort_t* outp; int ldo;
    if (z == 0)      { in = Wo;                 outp = WoT;      ldo = ID; }
    else if (z == 1) { in = Wg;                 outp = WgT;      ldo = 2 * HD; }
    else             { in = Wg + (long)HD * HD; outp = WgT + HD; ldo = 2 * HD; }
    int r0 = (tile >> 5) * 32, c0 = (tile & 31) * 32;
    for (int i = ty; i < 32; i += 8)
        t1[i][tx] = in[(long)(r0 + i) * HD + c0 + tx];
    __syncthreads();
    for (int i = ty; i < 32; i += 8)
        outp[(long)(c0 + i) * ldo + r0 + tx] = f2bf(t1[tx][i]);
}

// ---------- bf16 MFMA GEMM: C = alpha*(A @ Bt^T) + add0 + bias [+ C] ----------
// A = [A0 | A1] two optional K-segments (each KSEG wide), bf16 row-major.
// Bt [N, Ktot] bf16 row-major. C fp32 or bf16 (fl&1).
// fl&2: skip tiles N0>M0. fl&4: accumulate into f32 C (RMW).
// fl&8: M-valid = 64 (upper waves skip stores).
// flags&16: DUAL mode — blockIdx.z==1 selects {Bt2, Cv2, bias2, flags2}; z-batch offsets = 0.
// 128x128 tile, BK=32, 4 waves each 64x64 via 4x4 mfma_f32_16x16x32_bf16.
__global__ __launch_bounds__(256, 3) void gemm_bf16(
    const ushort_t* __restrict__ A0, long sA0, int lda0,
    const ushort_t* __restrict__ A1, long sA1, int lda1,
    const ushort_t* __restrict__ Bt, long sBb, int ldb,
    void* __restrict__ Cv, long sCb, int ldc,
    int KSEG, const float* __restrict__ bias,
    float alpha, float add0, int flags,
    const ushort_t* __restrict__ Bt2, void* __restrict__ Cv2,
    const float* __restrict__ bias2, int flags2)
{
    long zb = blockIdx.z;
    int fl = flags;
    if (flags & 16) {
        zb = 0;
        if (blockIdx.z == 1) { Bt = Bt2; Cv = Cv2; bias = bias2; fl = flags2; }
    }
    int bx, by;
    {
        int L = blockIdx.y * gridDim.x + blockIdx.x;
        if ((gridDim.y & 7) == 0) {
            int xcd = L & 7, g = L >> 3;
            bx = g % gridDim.x;
            by = (g / gridDim.x) * 8 + xcd;
        } else { bx = blockIdx.x; by = blockIdx.y; }
    }
    const int M0 = by * 128, N0 = bx * 128;
    if ((fl & 2) && N0 > M0) return;

    __shared__ ushort_t As[128 * 32];
    __shared__ ushort_t Bs[128 * 32];
    const int tid = threadIdx.x;
    const int wave = tid >> 6, lane = tid & 63;
    const int lr = lane & 15, lq = lane >> 4;
    const int wm = (wave & 1) * 64, wn = (wave >> 1) * 64;

    ushort_t* la0 = &As[(wave * 16)      * 32];
    ushort_t* la1 = &As[(wave * 16 + 64) * 32];
    ushort_t* lb0 = &Bs[(wave * 16)      * 32];
    ushort_t* lb1 = &Bs[(wave * 16 + 64) * 32];

    const ushort_t* gb0 = Bt + zb * sBb
                        + (long)(N0 + wave * 16 + (lane >> 2)) * ldb + (lane & 3) * 8;
    const ushort_t* gb1 = gb0 + 64L * ldb;

    floatx4 acc[4][4] = {};

    for (int seg = 0; seg < 2; ++seg) {
        const ushort_t* Ag = (seg == 0) ? A0 : A1;
        if (!Ag) break;
        const int lda = (seg == 0) ? lda0 : lda1;
        Ag += zb * ((seg == 0) ? sA0 : sA1);
        const ushort_t* ga0 = Ag + (long)(M0 + wave * 16 + (lane >> 2)) * lda + (lane & 3) * 8;
        const ushort_t* ga1 = ga0 + 64L * lda;

        for (int k0 = 0; k0 < KSEG; k0 += 32) {
            load_lds16(ga0, la0);
            load_lds16(ga1, la1);
            load_lds16(gb0, lb0);
            load_lds16(gb1, lb1);
            ga0 += 32; ga1 += 32; gb0 += 32; gb1 += 32;
            __syncthreads();
            short8 af[4], bf4[4];
#pragma unroll
            for (int i = 0; i < 4; ++i)
                af[i] = *(const short8*)&As[(wm + i * 16 + lr) * 32 + lq * 8];
#pragma unroll
            for (int j = 0; j < 4; ++j)
                bf4[j] = *(const short8*)&Bs[(wn + j * 16 + lr) * 32 + lq * 8];
#pragma unroll
            for (int i = 0; i < 4; ++i)
#pragma unroll
                for (int j = 0; j < 4; ++j)
                    acc[i][j] = __builtin_amdgcn_mfma_f32_16x16x32_bf16(
                        af[i], bf4[j], acc[i][j], 0, 0, 0);
            __syncthreads();
        }
    }

    // C/D layout: col = lane&15, row = (lane>>4)*4 + reg
    float bv[4] = {0.f, 0.f, 0.f, 0.f};
    if (bias) {
#pragma unroll
        for (int j = 0; j < 4; ++j) bv[j] = bias[N0 + wn + j * 16 + lr];
    }
    if (fl & 1) {
        ushort_t* C = (ushort_t*)Cv + zb * sCb;
#pragma unroll
        for (int i = 0; i < 4; ++i)
#pragma unroll
            for (int r = 0; r < 4; ++r) {
                int row = M0 + wm + i * 16 + lq * 4 + r;
                ushort_t* cp = C + (long)row * ldc + N0 + wn + lr;
#pragma unroll
                for (int j = 0; j < 4; ++j)
                    cp[j * 16] = f2bf(alpha * acc[i][j][r] + add0 + bv[j]);
            }
    } else {
        if ((fl & 8) && wm) return;
        float* C = (float*)Cv + zb * sCb;
#pragma unroll
        for (int i = 0; i < 4; ++i)
#pragma unroll
            for (int r = 0; r < 4; ++r) {
                int row = M0 + wm + i * 16 + lq * 4 + r;
                float* cp = C + (long)row * ldc + N0 + wn + lr;
#pragma unroll
                for (int j = 0; j < 4; ++j) {
                    float val = alpha * acc[i][j][r] + add0 + bv[j];
                    if (fl & 4) val += cp[j * 16];
                    cp[j * 16] = val;
                }
            }
    }
}

// ---------- per-chunk solve (8 launches, 512 threads = 8 waves for BW occupancy) ----------
// Grid (4, 1, BATCH) = 256 blocks, 512 threads. Block owns a 64x256 slab of one batch.
// Diagnosis r3==r6: solve is HBM-BW-bound at 4 waves/CU. This version keeps LDS and
// arithmetic IDENTICAL but runs 8 waves/block (1 block/CU -> 8 waves/CU, 2x):
//  * MFMA: wave w owns cols w*32..w*32+31 (acc[4][2]); same 64 MFMA/k-step total.
//  * staging: every wave stages its own 32 B-rows; waves 0-3 also stage 16 A-rows.
//  * recurrence: tid<256 (1 thread/col), then e -> Us so ALL 512 threads do the
//    BW-heavy EbT + silu phases (each thread: one 32-row half-column).
__global__ __launch_bounds__(512) void solve_chunk(const float* __restrict__ u,
                                                   const ushort_t* __restrict__ gram,
                                                   ushort_t* __restrict__ ebt,
                                                   ushort_t* __restrict__ tgtb, int c)
{
    const int b = blockIdx.z;
    const int j0 = blockIdx.x << 8;          // 0,256,512,768
    const int t0 = c << 6;
    const int tid = threadIdx.x;
    const int wave = tid >> 6, lane = tid & 63;
    const int lr = lane & 15, lq = lane >> 4;

    __shared__ float Us[64][260];                        // 66.5 KB slab (stride 260)
    __shared__ __align__(16) char smem2[2][20480];       // 2 x (As 4KB | Bs 16KB)
    float* Gs = (float*)smem2;                           // 16 KB overlay (post-loop)

    const ushort_t* Gb = gram + (long)b * SEQ * SEQ + (long)t0 * SEQ;   // 64 x SEQ
    const float* Ub = u + (long)b * SEQ * ID + (long)t0 * ID;           // 64 x ID
    ushort_t* Eb = ebt + (long)b * ID * SEQ;                            // ID x SEQ

    // ---- u-slab prefetch: 8 rows (1KB each) per wave, 16B/lane
    {
        const int r0w = wave * 8;
#pragma unroll
        for (int r = 0; r < 8; ++r)
            load_lds16(Ub + (long)(r0w + r) * ID + j0 + (lane << 2), &Us[r0w + r][0]);
    }

    if (c > 0) {
        const int K = c << 6;
        floatx4 acc[4][2] = {};
        const int brow = wave * 32;              // this wave's col/B-row base (0..224)
        const int srow = lane >> 2, scol = (lane & 3) * 8;

        auto stage = [&](int bsel, int k0) {
            ushort_t* As_ = (ushort_t*)smem2[bsel];
            ushort_t* Bs_ = (ushort_t*)(smem2[bsel] + 4096);
            if (wave < 4)
                load_lds16(Gb + (long)(wave * 16 + srow) * SEQ + scol + k0,
                           &As_[(wave * 16) * 32]);
            load_lds16(Eb + (long)(j0 + brow + srow) * SEQ + scol + k0,
                       &Bs_[(brow) * 32]);
            load_lds16(Eb + (long)(j0 + brow + 16 + srow) * SEQ + scol + k0,
                       &Bs_[(brow + 16) * 32]);
        };

        stage(0, 0);
        __syncthreads();                     // buf0 ready (also drains u-prefetch)
        int buf = 0;
        for (int k0 = 0; k0 < K; k0 += 32) {
            if (k0 + 32 < K) stage(buf ^ 1, k0 + 32);   // issue next BEFORE compute
            const ushort_t* As_ = (const ushort_t*)smem2[buf];
            const ushort_t* Bs_ = (const ushort_t*)(smem2[buf] + 4096);
            short8 af[4], bfr[2];
#pragma unroll
            for (int i = 0; i < 4; ++i)
                af[i] = *(const short8*)&As_[(i * 16 + lr) * 32 + lq * 8];
#pragma unroll
            for (int j = 0; j < 2; ++j)
                bfr[j] = *(const short8*)&Bs_[(brow + j * 16 + lr) * 32 + lq * 8];
#pragma unroll
            for (int i = 0; i < 4; ++i)
#pragma unroll
                for (int j = 0; j < 2; ++j)
                    acc[i][j] = __builtin_amdgcn_mfma_f32_16x16x32_bf16(
                        af[i], bfr[j], acc[i][j], 0, 0, 0);
            __syncthreads();                 // drains next-stage loads (issued early)
            buf ^= 1;
        }
        // epilogue: Us -= acc  (C/D layout: col=lane&15, row=lq*4+reg)
#pragma unroll
        for (int i = 0; i < 4; ++i)
#pragma unroll
            for (int r = 0; r < 4; ++r) {
                int row = i * 16 + lq * 4 + r;
#pragma unroll
                for (int j = 0; j < 2; ++j)
                    Us[row][brow + j * 16 + lr] -= acc[i][j][r];
            }
    }

    // stage G diag block (bf16 -> f32 LDS; overlays As/Bs — past last read+barrier)
    if (tid < 512) {
        int row = tid >> 3, col8 = (tid & 7) << 3;
        ushort8 g8 = *(const ushort8*)(Gb + (long)row * SEQ + t0 + col8);
#pragma unroll
        for (int k = 0; k < 8; ++k) Gs[row * 64 + col8 + k] = bf2f(g8[k]);
    }
    __syncthreads();   // Us (prefetch +/- acc) complete, Gs complete (drains vmcnt)

    // intra-chunk forward substitution, one column per thread (tid<256; all LDS)
    if (tid < 256) {
        float e[64];
        e[0] = Us[0][tid];
#pragma unroll
        for (int t = 1; t < 64; ++t) {
            float v = Us[t][tid];
            float p0 = 0.f, p1 = 0.f, p2 = 0.f, p3 = 0.f;   // 4-way ILP on the chain
#pragma unroll
            for (int s = 0; s + 3 < t; s += 4) {
                p0 = fmaf(Gs[t * 64 + s + 0], e[s + 0], p0);
                p1 = fmaf(Gs[t * 64 + s + 1], e[s + 1], p1);
                p2 = fmaf(Gs[t * 64 + s + 2], e[s + 2], p2);
                p3 = fmaf(Gs[t * 64 + s + 3], e[s + 3], p3);
            }
#pragma unroll
            for (int s = t & ~3; s < t; ++s)
                p0 = fmaf(Gs[t * 64 + s], e[s], p0);
            e[t] = v - ((p0 + p1) + (p2 + p3));
        }
        // writeback so all 512 threads can run the BW phases (per-thread column: safe)
#pragma unroll
        for (int t = 0; t < 64; ++t) Us[t][tid] = e[t];
    }
    __syncthreads();

    const int col = tid & 255, half = tid >> 8;   // half-column split across 512 threads

    // transposed bf16 copy for later chunks' MFMA updates
    if (c < NCHUNK - 1) {
        ushort_t* EB = Eb + (long)(j0 + col) * SEQ + t0 + half * 32;
#pragma unroll
        for (int g = 0; g < 4; ++g) {
            ushort8 o;
#pragma unroll
            for (int k = 0; k < 8; ++k) o[k] = f2bf(Us[half * 32 + g * 8 + k][col]);
            *(ushort8*)(EB + g * 8) = o;
        }
    }

    // fused silu, in place over tgtb (tgtb becomes hb); 128B/row per wave, coalesced
    ushort_t* Tp = tgtb + ((long)b * SEQ + t0 + half * 32) * ID + j0 + col;
#pragma unroll
    for (int t = 0; t < 32; ++t) {
        float v = Us[half * 32 + t][col] + bf2f(Tp[(long)t * ID]);
        Tp[(long)t * ID] = f2bf(v / (1.0f + __expf(-v)));
    }
}

// ---------- gate + residual mix + LayerNorm (z, ttt in bf16) ----------
__global__ __launch_bounds__(256) void gate_ln(
    const ushort_t* __restrict__ zb, const ushort_t* __restrict__ tttb,
    const float* __restrict__ x, const float* __restrict__ gamma,
    const float* __restrict__ bet, float* __restrict__ out)
{
    long base = (long)blockIdx.x * HD + threadIdx.x * 4;
    ushort4v zv4 = *(const ushort4v*)(zb + base);
    ushort4v tv4 = *(const ushort4v*)(tttb + base);
    float4 xv = *(const float4*)(x + base);
    float xr[4] = {xv.x, xv.y, xv.z, xv.w};
    float y[4];
#pragma unroll
    for (int k = 0; k < 4; ++k) {
        float g = 1.0f / (1.0f + __expf(-bf2f(zv4[k])));
        float t = bf2f(tv4[k]);
        y[k] = g * t + (1.0f - g) * xr[k];
    }
    float sum = y[0] + y[1] + y[2] + y[3];
    float sq  = y[0]*y[0] + y[1]*y[1] + y[2]*y[2] + y[3]*y[3];
#pragma unroll
    for (int off = 32; off > 0; off >>= 1) {
        sum += __shfl_down(sum, off);
        sq  += __shfl_down(sq, off);
    }
    __shared__ float s1[4], s2[4];
    int wid = threadIdx.x >> 6;
    if ((threadIdx.x & 63) == 0) { s1[wid] = sum; s2[wid] = sq; }
    __syncthreads();
    float tot = s1[0] + s1[1] + s1[2] + s1[3];
    float tsq = s2[0] + s2[1] + s2[2] + s2[3];
    float mu = tot * (1.0f / HD);
    float var = tsq * (1.0f / HD) - mu * mu;
    float rs = rsqrtf(var + 1e-5f);
    int col = threadIdx.x * 4;
    float4 ov;
    ov.x = (y[0] - mu) * rs * gamma[col + 0] + bet[col + 0];
    ov.y = (y[1] - mu) * rs * gamma[col + 1] + bet[col + 1];
    ov.z = (y[2] - mu) * rs * gamma[col + 2] + bet[col + 2];
    ov.w = (y[3] - mu) * rs * gamma[col + 3] + bet[col + 3];
    *(float4*)(out + base) = ov;
}

extern "C" void kernel_launch(void* const* d_in, const int* in_sizes, int n_in,
                              void* d_out, int out_size, void* d_ws, size_t ws_size,
                              hipStream_t stream)
{
    const float* x    = (const float*)d_in[0];
    const float* Wi   = (const float*)d_in[1];
    const float* bi   = (const float*)d_in[2];
    const float* Wt   = (const float*)d_in[3];
    const float* bt   = (const float*)d_in[4];
    const float* Wo   = (const float*)d_in[5];
    const float* bo   = (const float*)d_in[6];
    const float* Wg   = (const float*)d_in[7];
    const float* bg   = (const float*)d_in[8];
    const float* gam  = (const float*)d_in[9];
    const float* bet  = (const float*)d_in[10];
    float* out = (float*)d_out;

    // Workspace ~394 MB (unchanged footprint):
    //   u    [BS,ID] f32 128MB : RHS (read-only during solve); AFTER solve reused as zb bf16
    //   tgtb [BS,ID] bf16 64MB : target; solve_chunk silu-rewrites IN PLACE -> becomes hb
    //   gram region       64MB : gramb bf16 [B,S,S] (32MB); dead after solve
    //   xb   [BS,HD] bf16 64MB : x bf16 (live until z GEMM)
    //   tttb [BS,HD] bf16 64MB : DURING solve overlaid by EbT bf16 [B,ID,SEQ]; after: ttt
    //   weights bf16 ~10MB + bd
    float* u       = (float*)d_ws;
    ushort_t* tgtb = (ushort_t*)(u + (long)BS * ID);
    float* gram    = (float*)(tgtb + (long)BS * ID);
    ushort_t* xb   = (ushort_t*)(gram + (long)BATCH * SEQ * SEQ);
    ushort_t* tttb = xb + (long)BS * HD;
    ushort_t* WdT  = tttb + (long)BS * HD;            // [ID,HD]
    ushort_t* WtT  = WdT + (long)HD * ID;             // [ID,HD]
    ushort_t* WoT  = WtT + (long)HD * ID;             // [HD,ID]
    ushort_t* WgT  = WoT + (long)HD * ID;             // [HD, 2*HD] concat K
    float* bd      = (float*)(WgT + (long)HD * 2 * HD);
    ushort_t* gramb = (ushort_t*)gram;                // gram stored bf16
    ushort_t* ebt   = (ushort_t*)tttb;                // overlay: EbT during solve
    ushort_t* hb    = tgtb;                           // after solve: silu output in place
    ushort_t* zb    = (ushort_t*)u;                   // overlay: after solve

    // ---- prep (1 launch: convert + prep_w + 3 transposes) ----
    prep_all<<<16384 + 1024 + 3072, 256, 0, stream>>>(
        x, xb, Wi, Wt, WdT, WtT, bi, bt, bd, Wo, Wg, WoT, WgT);

    dim3 gBig(ID / 128, BS / 128, 1);   // 8 x 256
    // DUAL: z=0: u = x @ (Wi - Wt) + (bi - bt) [f32]; z=1: target = x @ Wt + bt [bf16]
    gemm_bf16<<<dim3(ID / 128, BS / 128, 2), 256, 0, stream>>>(
        xb, 0, HD, nullptr, 0, 0, WdT, 0, HD,
        u, 0, ID, HD, bd, 1.f, 0.f, 16,
        WtT, tgtb, bt, 1);
    // gram = (LR/I) * (X X^T + 1)     [bf16 out, lower tiles only]
    gemm_bf16<<<dim3(SEQ / 128, SEQ / 128, BATCH), 256, 0, stream>>>(
        xb, (long)SEQ * HD, HD, nullptr, 0, 0, xb, (long)SEQ * HD, HD,
        gramb, (long)SEQ * SEQ, SEQ, HD, nullptr, LR_OVER_I, LR_OVER_I, 2 | 1,
        nullptr, nullptr, nullptr, 0);

    // ---- blocked forward substitution + fused silu (8 launches, 512-thread blocks) ----
    for (int c = 0; c < NCHUNK; ++c)
        solve_chunk<<<dim3(4, 1, BATCH), 512, 0, stream>>>(u, gramb, ebt, tgtb, c);

    // ttt = h @ Wo + bo               [bf16 out; hb == tgtb in place]
    gemm_bf16<<<gBig, 256, 0, stream>>>(hb, 0, ID, nullptr, 0, 0, WoT, 0, ID,
                                        tttb, 0, HD, ID, bo, 1.f, 0.f, 1,
                                        nullptr, nullptr, nullptr, 0);
    // z = [x, ttt] @ Wg + bg          [bf16 out, two K-segments; zb overlays u]
    gemm_bf16<<<gBig, 256, 0, stream>>>(xb, 0, HD, tttb, 0, HD, WgT, 0, 2 * HD,
                                        zb, 0, HD, HD, bg, 1.f, 0.f, 1,
                                        nullptr, nullptr, nullptr, 0);
    // out = LN(g*ttt + (1-g)*x)
    gate_ln<<<BS, 256, 0, stream>>>(zb, tttb, x, gam, bet, out);
}